// Round 10
// baseline (64.647 us; speedup 1.0000x reference)
//
#include <hip/hip_runtime.h>

// Fused 6-layer MLP, v11: row-at-a-time, fully-contiguous x reads.
// Wave processes 8 rows (4 passes x 2 rows, W shared per pass); lane = k-chunk:
// x loads are 64-lane x 16B = 1024B contiguous bursts (fill-like DRAM pattern).
// W1 in LDS as bf16 k-pairs [pair p][j] padded to 13 u32 (stride 52B,
// gcd(13,32)=1 -> conflict-free ds_read2_b32). v10's dot2 compute.
// 64-lane reduce: DPP row_ror to 4 group-partials, leaders write to
// wave-private LDS, epilogue (v2's proven store code) on lanes<32. No
// main-loop barriers. Block 256 = 4 waves = 32 rows; grid 2048.

__device__ __forceinline__ float ftanh(float v) {
    float e = __expf(2.0f * v);
    return 1.0f - 2.0f / (e + 1.0f);
}

__device__ __forceinline__ uint32_t cvtpk(float lo, float hi) {
    uint32_t d;
    asm("v_cvt_pk_bf16_f32 %0, %1, %2" : "=v"(d) : "v"(lo), "v"(hi));
    return d;
}

__device__ __forceinline__ float dot2(uint32_t a, uint32_t b, float c) {
    float d;
    asm("v_dot2_f32_bf16 %0, %1, %2, %3" : "=v"(d) : "v"(a), "v"(b), "v"(c));
    return d;
}

template <int CTRL>
__device__ __forceinline__ float dpp_add(float v) {
    int m = __builtin_amdgcn_update_dpp(0, __float_as_int(v), CTRL, 0xF, 0xF, false);
    return v + __int_as_float(m);
}

// sum within each 16-lane group: row_ror 8,4,2,1 (pure VALU)
__device__ __forceinline__ float rowsum16(float v) {
    v = dpp_add<0x128>(v);
    v = dpp_add<0x124>(v);
    v = dpp_add<0x122>(v);
    v = dpp_add<0x121>(v);
    return v;
}

__global__ __launch_bounds__(256, 4)
void mlp_fused11(const float* __restrict__ x,
                 const float* __restrict__ W1, const float* __restrict__ b1,
                 const float* __restrict__ W2, const float* __restrict__ b2,
                 const float* __restrict__ W3, const float* __restrict__ b3,
                 const float* __restrict__ W4, const float* __restrict__ b4,
                 const float* __restrict__ W5, const float* __restrict__ b5,
                 const float* __restrict__ W6, const float* __restrict__ b6,
                 float* __restrict__ out)
{
    __shared__ uint32_t ldsW[392 * 13];     // 20384 B, [pair p][j] pad-13
    __shared__ float h1p[4][8][4][12];      // 6144 B, [wave][row][grp][j]

    const int tid = threadIdx.x;

    // ---- stage W1 -> LDS as packed bf16 k-pairs (RNE via cvt_pk) ----
    for (int t = tid; t < 4704; t += 256) {
        int p = t / 12, j = t - p * 12;
        ldsW[p * 13 + j] = cvtpk(W1[p * 24 + j], W1[p * 24 + 12 + j]);
    }
    __syncthreads();

    const int wave = tid >> 6;
    const int L    = tid & 63;
    const int row0 = (blockIdx.x << 5) + (wave << 3);   // 8 rows per wave
    const float* xr = x + (size_t)row0 * 784;

    const int  tp   = 384 + (L & 7);        // tail pair (8 pairs, lanes 0..7)
    const bool tact = (L < 8);

    for (int pass = 0; pass < 4; ++pass) {
        const float* pA = xr + (size_t)(2 * pass) * 784;
        const float* pB = pA + 784;

        float accA[12], accB[12];
#pragma unroll
        for (int j = 0; j < 12; ++j) { accA[j] = 0.f; accB[j] = 0.f; }

#pragma unroll
        for (int s = 0; s < 3; ++s) {
            float4 xa = *(const float4*)(pA + 4 * (s * 64 + L));   // 1024B/wave
            float4 xb = *(const float4*)(pB + 4 * (s * 64 + L));
            const int p0 = 2 * (s * 64 + L);                        // pairs p0,p0+1

            uint32_t w0[12], w1[12];
#pragma unroll
            for (int j = 0; j < 12; ++j) {
                w0[j] = ldsW[p0 * 13 + j];
                w1[j] = ldsW[p0 * 13 + 13 + j];
            }

            uint32_t xa0 = cvtpk(xa.x, xa.y), xa1 = cvtpk(xa.z, xa.w);
            uint32_t xb0 = cvtpk(xb.x, xb.y), xb1 = cvtpk(xb.z, xb.w);

#pragma unroll
            for (int j = 0; j < 12; ++j) {
                accA[j] = dot2(xa0, w0[j], accA[j]);
                accA[j] = dot2(xa1, w1[j], accA[j]);
                accB[j] = dot2(xb0, w0[j], accB[j]);
                accB[j] = dot2(xb1, w1[j], accB[j]);
            }
        }
        {   // k-tail: pairs 384..391 on lanes 0..7, x masked to 0 elsewhere
            float2 ta = *(const float2*)(pA + 2 * tp);
            float2 tb = *(const float2*)(pB + 2 * tp);
            uint32_t xpa = tact ? cvtpk(ta.x, ta.y) : 0u;
            uint32_t xpb = tact ? cvtpk(tb.x, tb.y) : 0u;
            uint32_t wt[12];
#pragma unroll
            for (int j = 0; j < 12; ++j) wt[j] = ldsW[tp * 13 + j];
#pragma unroll
            for (int j = 0; j < 12; ++j) {
                accA[j] = dot2(xpa, wt[j], accA[j]);
                accB[j] = dot2(xpb, wt[j], accB[j]);
            }
        }

        // ---- reduce to 4 group-partials, leaders write (wave-private) ----
#pragma unroll
        for (int j = 0; j < 12; ++j) {
            accA[j] = rowsum16(accA[j]);
            accB[j] = rowsum16(accB[j]);
        }
        if ((L & 15) == 0) {
            const int g = L >> 4;
            float4* qa = (float4*)&h1p[wave][2 * pass][g][0];
            qa[0] = make_float4(accA[0], accA[1], accA[2],  accA[3]);
            qa[1] = make_float4(accA[4], accA[5], accA[6],  accA[7]);
            qa[2] = make_float4(accA[8], accA[9], accA[10], accA[11]);
            float4* qb = (float4*)&h1p[wave][2 * pass + 1][g][0];
            qb[0] = make_float4(accB[0], accB[1], accB[2],  accB[3]);
            qb[1] = make_float4(accB[4], accB[5], accB[6],  accB[7]);
            qb[2] = make_float4(accB[8], accB[9], accB[10], accB[11]);
        }
    }

    // ---- epilogue: lanes < 32, 4 lanes per row (same wave; no barrier) ----
    if (L < 32) {
        const int r   = L >> 2;
        const int sub = L & 3;
        const int row = row0 + r;

        const float4* pp = (const float4*)&h1p[wave][r][sub][0];
        float4 a0 = pp[0], a1 = pp[1], a2 = pp[2];

        float h1[12];
#define REDJ(dst, v0)                                                      \
        { float v = (v0); v += __shfl_xor(v, 1); v += __shfl_xor(v, 2); dst = v; }
        REDJ(h1[0],  a0.x) REDJ(h1[1],  a0.y) REDJ(h1[2],  a0.z) REDJ(h1[3],  a0.w)
        REDJ(h1[4],  a1.x) REDJ(h1[5],  a1.y) REDJ(h1[6],  a1.z) REDJ(h1[7],  a1.w)
        REDJ(h1[8],  a2.x) REDJ(h1[9],  a2.y) REDJ(h1[10], a2.z) REDJ(h1[11], a2.w)
#undef REDJ
#pragma unroll
        for (int j = 0; j < 12; ++j) h1[j] = ftanh(h1[j] + b1[j]);

        float h2[10];
#pragma unroll
        for (int m = 0; m < 10; ++m) {
            float s = b2[m];
#pragma unroll
            for (int j = 0; j < 12; ++j) s += h1[j] * W2[j * 10 + m];
            h2[m] = ftanh(s);
        }
        float h3[8];
#pragma unroll
        for (int m = 0; m < 8; ++m) {
            float s = b3[m];
#pragma unroll
            for (int j = 0; j < 10; ++j) s += h2[j] * W3[j * 8 + m];
            h3[m] = ftanh(s);
        }
        float h4[6];
#pragma unroll
        for (int m = 0; m < 6; ++m) {
            float s = b4[m];
#pragma unroll
            for (int j = 0; j < 8; ++j) s += h3[j] * W4[j * 6 + m];
            h4[m] = ftanh(s);
        }
        float h5[4];
#pragma unroll
        for (int m = 0; m < 4; ++m) {
            float s = b5[m];
#pragma unroll
            for (int j = 0; j < 6; ++j) s += h4[j] * W5[j * 4 + m];
            h5[m] = ftanh(s);
        }
        float o[10];
#pragma unroll
        for (int m = 0; m < 10; ++m) {
            float s = b6[m];
#pragma unroll
            for (int j = 0; j < 4; ++j) s += h5[j] * W6[j * 10 + m];
            o[m] = s;   // logits
        }

        const size_t H1 = 655360, H2 = 1441792, H3 = 2097152, H4 = 2621440, H5 = 3014656;
        float2* po  = (float2*)(out +      (size_t)row * 10);
        float4* ph1 = (float4*)(out + H1 + (size_t)row * 12);
        float2* ph2 = (float2*)(out + H2 + (size_t)row * 10);
        float4* ph3 = (float4*)(out + H3 + (size_t)row * 8);
        float2* ph4 = (float2*)(out + H4 + (size_t)row * 6);
        float4* ph5 = (float4*)(out + H5 + (size_t)row * 4);

        if (sub == 0) {
            po[0]  = make_float2(o[0], o[1]);
            po[4]  = make_float2(o[8], o[9]);
            ph2[0] = make_float2(h2[0], h2[1]);
            ph2[4] = make_float2(h2[8], h2[9]);
            ph4[1] = make_float2(h4[2], h4[3]);
        } else if (sub == 1) {
            po[1]  = make_float2(o[2], o[3]);
            ph1[0] = make_float4(h1[0], h1[1], h1[2], h1[3]);
            ph2[1] = make_float2(h2[2], h2[3]);
            ph3[0] = make_float4(h3[0], h3[1], h3[2], h3[3]);
            ph4[2] = make_float2(h4[4], h4[5]);
        } else if (sub == 2) {
            po[2]  = make_float2(o[4], o[5]);
            ph1[1] = make_float4(h1[4], h1[5], h1[6], h1[7]);
            ph2[2] = make_float2(h2[4], h2[5]);
            ph3[1] = make_float4(h3[4], h3[5], h3[6], h3[7]);
            ph5[0] = make_float4(h5[0], h5[1], h5[2], h5[3]);
        } else {
            po[3]  = make_float2(o[6], o[7]);
            ph1[2] = make_float4(h1[8], h1[9], h1[10], h1[11]);
            ph2[3] = make_float2(h2[6], h2[7]);
            ph4[0] = make_float2(h4[0], h4[1]);
        }
    }
}

extern "C" void kernel_launch(void* const* d_in, const int* in_sizes, int n_in,
                              void* d_out, int out_size, void* d_ws, size_t ws_size,
                              hipStream_t stream) {
    (void)in_sizes; (void)n_in; (void)d_ws; (void)ws_size; (void)out_size;
    mlp_fused11<<<2048, 256, 0, stream>>>(
        (const float*)d_in[0],
        (const float*)d_in[1],  (const float*)d_in[2],
        (const float*)d_in[3],  (const float*)d_in[4],
        (const float*)d_in[5],  (const float*)d_in[6],
        (const float*)d_in[7],  (const float*)d_in[8],
        (const float*)d_in[9],  (const float*)d_in[10],
        (const float*)d_in[11], (const float*)d_in[12],
        (float*)d_out);
}